// Round 6
// baseline (1881.271 us; speedup 1.0000x reference)
//
// EpisodicMemory: fp32 inputs/output.
//   prep_w    : one-shot fp32->bf16 conversion of fc1_w, W_ih, W_hh into ws.
//   g_kernel  : per-b block, feat@fc1w^T via 16x16x32 bf16 MFMA (unchanged; 131us,
//               later-round target).
//   scan_all  : R10 — resubmission of R9 (bench infra died: "container failed
//               twice", push times degrading 0->525->1308s; kernel re-audited:
//               no deadlock [flag precedes poll, no circular wait], no OOB
//               [all indices walked], launch geometry proven by R7/R8).
//               R4 falsified the LDS-pipeline theory (LDS traffic -40%, time
//               unchanged; 3 structurally different kernels all ~20.5us/step,
//               stall ~75%). Shared causes attacked here:
//               (a) 1 wave/SIMD -> ALL latencies exposed. Now 512-thr blocks
//                   (8 waves = 2/SIMD), same 256-block grid & group structure.
//               (b) barrier round trip naked on critical path. Now gate split:
//                   PhaseB = C(t)@Wih (h-independent, C direct from L2 as
//                   per-lane frags, no LDS, no syncs) runs BETWEEN flag and
//                   poll -> barrier latency hides under ~1/3 of MFMAs.
//                   PhaseA = h@Whh (LDS-staged h hi/lo, dbuf) after the poll,
//                   same accumulators (acc order changes, ~1e-6 drift).
//               (c) h loads lane-consecutive (coalesced 16B) vs 64B-stride.
//               (d) per-wave poll (no post-poll sync skew), s_sleep(1).
//               Barrier mechanism itself = R7's proven fence-free progress slots:
//               vmcnt(0) all waves -> syncthreads -> t0 flags -> members poll.
//               h packed (hi<<16|lo) sc0sc1 (bypasses non-coherent L2s) dbuf.
//               LDS: Whh 97.5K + As(h hi/lo x 2buf) 36K = 133.5KB -> 1 block/CU.
#include <hip/hip_runtime.h>
#include <hip/hip_bf16.h>

#define H_ 512
#define SH_ 120
#define B_ 1024
#define S_ 64

typedef __bf16 bf16x8 __attribute__((ext_vector_type(8)));
typedef float floatx4 __attribute__((ext_vector_type(4)));

__device__ __forceinline__ float bf2f(ushort u) {
    union { unsigned int i; float f; } v; v.i = ((unsigned int)u) << 16; return v.f;
}
__device__ __forceinline__ ushort f2bf(float f) {
    union { float f; unsigned int i; } v; v.f = f;
    unsigned int x = v.i;
    unsigned int r = (x + 0x7fffu + ((x >> 16) & 1u)) >> 16;  // RNE
    return (ushort)r;
}

// Per-(group, member) progress slots. Group = b-tile (16 blocks), member = j-tile.
// Single writer per slot, monotone, never reset -> replay/graph-safe.
__device__ __attribute__((aligned(64))) unsigned g_prog[256];

// ---------------------------------------------------------------------------
// prep_w: one-shot fp32 -> bf16 of the three weight matrices.
// ---------------------------------------------------------------------------
__global__ __launch_bounds__(256) void prep_w(
    const float* __restrict__ fc1w, ushort* __restrict__ fc1wb,
    const float* __restrict__ Wih,  ushort* __restrict__ Wihb,
    const float* __restrict__ Whh,  ushort* __restrict__ Whhb)
{
    const int stride = gridDim.x * blockDim.x;
    const int tid = blockIdx.x * blockDim.x + threadIdx.x;
    for (int i = tid; i < 61440; i += stride) {            // 120*2048/4
        const float4 v = ((const float4*)fc1w)[i];
        ushort4 o; o.x = f2bf(v.x); o.y = f2bf(v.y); o.z = f2bf(v.z); o.w = f2bf(v.w);
        ((ushort4*)fc1wb)[i] = o;
    }
    for (int i = tid; i < 196608; i += stride) {           // 1536*512/4
        const float4 v = ((const float4*)Wih)[i];
        ushort4 o; o.x = f2bf(v.x); o.y = f2bf(v.y); o.z = f2bf(v.z); o.w = f2bf(v.w);
        ((ushort4*)Wihb)[i] = o;
    }
    for (int i = tid; i < 196608; i += stride) {
        const float4 v = ((const float4*)Whh)[i];
        ushort4 o; o.x = f2bf(v.x); o.y = f2bf(v.y); o.z = f2bf(v.z); o.w = f2bf(v.w);
        ((ushort4*)Whhb)[i] = o;
    }
}

// ---------------------------------------------------------------------------
// G kernel: one block per b. Computes G[b, s] for s=0..63. (unchanged)
// ---------------------------------------------------------------------------
__global__ __launch_bounds__(256) void g_kernel(
    const float* __restrict__ C, const float* __restrict__ Q,
    const float* __restrict__ M, const ushort* __restrict__ fc1wb,
    const float* __restrict__ fc1b, const float* __restrict__ fc2w,
    const float* __restrict__ fc2b, float* __restrict__ G)
{
    __shared__ float qrow[H_];
    __shared__ float mrow[H_];
    __shared__ __align__(16) ushort featT[64 * 72];   // 64 s-rows x 64 k (stride 72)
    __shared__ __align__(16) ushort wT[128 * 72];     // 128 n-rows x 64 k (rows>=120 zero)
    __shared__ float h1s[64 * 132];                   // 64 x 128 fp32 (stride 132)

    const int b = blockIdx.x;
    const int t = threadIdx.x;
    for (int i = t; i < H_; i += 256) { qrow[i] = Q[(size_t)b * H_ + i]; mrow[i] = M[(size_t)b * H_ + i]; }

    const int wrow = t >> 1;
    const int wc0  = (t & 1) * 32;
    if (wrow >= SH_) {              // zero-fill dead wT rows once
        uint4* dst = (uint4*)&wT[wrow * 72 + wc0];
        const uint4 z = {0u, 0u, 0u, 0u};
        dst[0] = z; dst[1] = z; dst[2] = z; dst[3] = z;
    }
    __syncthreads();

    const int lane = t & 63;
    const int wv   = t >> 6;
    const int quad = lane >> 4;
    const int l15  = lane & 15;
    const int arow = wv * 16 + l15;
    const int s    = t >> 2;
    const int c0   = (t & 3) * 16;

    floatx4 acc[8];
#pragma unroll
    for (int i = 0; i < 8; ++i) acc[i] = (floatx4){0.f, 0.f, 0.f, 0.f};

    for (int hc = 0; hc < H_; hc += 64) {
        float cr[16];
        {
            const float4* csrc = (const float4*)(C + ((size_t)b * S_ + s) * H_ + hc + c0);
            *(float4*)&cr[0]  = csrc[0];
            *(float4*)&cr[4]  = csrc[1];
            *(float4*)&cr[8]  = csrc[2];
            *(float4*)&cr[12] = csrc[3];
        }
#pragma unroll
        for (int seg = 0; seg < 4; ++seg) {
#pragma unroll
            for (int u = 0; u < 16; ++u) {
                const int kk = c0 + u;
                const float c = cr[u];
                const float o = (seg == 0 || seg == 2) ? qrow[hc + kk] : mrow[hc + kk];
                const float v = (seg < 2) ? c * o : fabsf(c - o);
                featT[s * 72 + kk] = f2bf(v);
            }
            if (wrow < SH_) {
                const uint4* src = (const uint4*)(fc1wb + (size_t)wrow * (4 * H_) + seg * H_ + hc + wc0);
                uint4* dst = (uint4*)&wT[wrow * 72 + wc0];
                dst[0] = src[0]; dst[1] = src[1]; dst[2] = src[2]; dst[3] = src[3];
            }
            __syncthreads();
#pragma unroll
            for (int ks = 0; ks < 64; ks += 32) {
                const int ao = ks + quad * 8;
                const bf16x8 af = *(const bf16x8*)&featT[arow * 72 + ao];
#pragma unroll
                for (int nt = 0; nt < 8; ++nt) {
                    const bf16x8 bfr = *(const bf16x8*)&wT[(nt * 16 + l15) * 72 + ao];
                    acc[nt] = __builtin_amdgcn_mfma_f32_16x16x32_bf16(af, bfr, acc[nt], 0, 0, 0);
                }
            }
            __syncthreads();
        }
    }

#pragma unroll
    for (int nt = 0; nt < 8; ++nt) {
        const int col = nt * 16 + l15;
        const float bias = (col < SH_) ? fc1b[col] : 0.f;
#pragma unroll
        for (int r = 0; r < 4; ++r) {
            const int row = wv * 16 + quad * 4 + r;
            h1s[row * 132 + col] = (col < SH_) ? tanhf(acc[nt][r] + bias) : 0.f;
        }
    }
    __syncthreads();
    {
        const int part = t & 3;
        float sum = 0.f;
        for (int k = part; k < SH_; k += 4) sum += h1s[s * 132 + k] * fc2w[k];
        sum += __shfl_xor(sum, 1);
        sum += __shfl_xor(sum, 2);
        if (part == 0) {
            const float logit = sum + fc2b[0];
            G[(size_t)b * S_ + s] = 1.f / (1.f + expf(-logit));
        }
    }
}

// ---------------------------------------------------------------------------
// scan_all: persistent scan. 256 blocks x 512 threads (8 waves = 2/SIMD),
// 1 block/CU (133.5 KB LDS). Block = (j-tile 32 cols) x (b-tile 64 batches).
// Wave w: row-half mh=w>>1 (16 rows), col-set cset=w&1 (3 of 6 (gate,jhalf)
// tiles). Whh slice LDS-resident. PhaseB (C@Wih, L2-direct, syncless) hides
// the inter-block barrier; PhaseA (h@Whh, LDS dbuf) after the poll.
// ---------------------------------------------------------------------------
__global__ __launch_bounds__(512) void scan_all(
    const float* __restrict__ C, const ushort* __restrict__ Wihb,
    const ushort* __restrict__ Whhb, const float* __restrict__ bih,
    const float* __restrict__ bhh, const float* __restrict__ G,
    uint* __restrict__ hp0, uint* __restrict__ hp1,
    float* __restrict__ out)
{
    __shared__ __align__(16) ushort Whh_s[96 * 520];   // 99840 B, persistent
    __shared__ __align__(16) ushort AsU[4 * 4608];     // [buf][hi|lo][64*72] 36864 B
    float* gs = (float*)AsU;                           // epilogue alias: 4 planes x 64x36

    const int bx = blockIdx.x;
    const int jt = bx >> 4;
    const int bt = ((bx & 7) << 1) | ((bx >> 3) & 1);  // group on one XCD (heuristic)
    const int jb = jt * 32;
    const int bb = bt * 64;
    const int t  = threadIdx.x;
    const int lane = t & 63;
    const int wv   = t >> 6;           // 0..7
    const int quad = lane >> 4;
    const int l15  = lane & 15;
    const int mh   = wv >> 1;          // 16-row half: rows mh*16..+15
    const int cset = wv & 1;           // col-tile triple {cset*3..+2}

    // --- barrier base: own slot, single-writer => exact, race-free ---
    const unsigned vbase = __hip_atomic_load(&g_prog[(bt << 4) + jt],
                                             __ATOMIC_RELAXED, __HIP_MEMORY_SCOPE_AGENT);

    // --- one-time: Whh slice (3 gates x 32 j-cols, full K) into LDS ---
#pragma unroll
    for (int i = 0; i < 12; ++i) {
        const int gid = i * 512 + t;          // 0..6143
        const int row = gid >> 6;             // 0..95
        const int grp = gid & 63;
        const int grow = (row >> 5) * H_ + jb + (row & 31);
        *(uint4*)&Whh_s[row * 520 + grp * 8] =
            *(const uint4*)(Whhb + (size_t)grow * H_ + grp * 8);
    }

    // --- hoisted biases ---
    float br_[2], bz_[2], bxn_[2], bhn_[2];
#pragma unroll
    for (int nt = 0; nt < 2; ++nt) {
        const int j = jb + nt * 16 + l15;
        br_[nt]  = bih[j] + bhh[j];
        bz_[nt]  = bih[H_ + j] + bhh[H_ + j];
        bxn_[nt] = bih[2 * H_ + j];
        bhn_[nt] = bhh[2 * H_ + j];
    }

    const int hold_kc  = (jb >> 6) << 6;
    const int hold_off = jb & 63;

    const uint* hr = hp0;   // read buffer (packed h)
    uint*       hw = hp1;   // write buffer

    unsigned long long hreg[4];   // 2 chunks x 16B of packed h

    auto load_h = [&](int kc) {   // coalesced: lane-consecutive 16B chunks
#pragma unroll
        for (int i = 0; i < 2; ++i) {
            const int chunk = i * 512 + t;    // 0..1023 (64 rows x 16 chunks)
            const int row = chunk >> 4;
            const int c4  = (chunk & 15) * 4;
            const unsigned long long* src = (const unsigned long long*)
                (hr + (size_t)(bb + row) * H_ + kc + c4);
            hreg[i * 2 + 0] = __hip_atomic_load(src,     __ATOMIC_RELAXED, __HIP_MEMORY_SCOPE_AGENT);
            hreg[i * 2 + 1] = __hip_atomic_load(src + 1, __ATOMIC_RELAXED, __HIP_MEMORY_SCOPE_AGENT);
        }
    };
    auto write_As = [&](int buf) {            // unpack packed h -> hi/lo planes
        ushort* hi_p = AsU + (buf * 2 + 0) * 4608;
        ushort* lo_p = AsU + (buf * 2 + 1) * 4608;
#pragma unroll
        for (int i = 0; i < 2; ++i) {
            const int chunk = i * 512 + t;
            const int row = chunk >> 4;
            const int c4  = (chunk & 15) * 4;
            const uint p0 = (uint)hreg[2 * i],     p1 = (uint)(hreg[2 * i] >> 32);
            const uint p2 = (uint)hreg[2 * i + 1], p3 = (uint)(hreg[2 * i + 1] >> 32);
            uint2 hi2, lo2;
            hi2.x = (p0 >> 16) | (p1 & 0xFFFF0000u);
            hi2.y = (p2 >> 16) | (p3 & 0xFFFF0000u);
            lo2.x = (p0 & 0xFFFFu) | (p1 << 16);
            lo2.y = (p2 & 0xFFFFu) | (p3 << 16);
            *(uint2*)&hi_p[row * 72 + c4] = hi2;
            *(uint2*)&lo_p[row * 72 + c4] = lo2;
        }
    };

    floatx4 accA[3], accB[2];
    auto zero_acc = [&]() {
#pragma unroll
        for (int i = 0; i < 3; ++i) accA[i] = (floatx4){0.f, 0.f, 0.f, 0.f};
#pragma unroll
        for (int i = 0; i < 2; ++i) accB[i] = (floatx4){0.f, 0.f, 0.f, 0.f};
    };

    // PhaseB: C(tstep)@Wih for this wave's tiles. L2-direct, no LDS, no syncs.
    auto phaseB = [&](int tstep) {
        const float* crow = C + ((size_t)(bb + mh * 16 + l15) * S_ + tstep) * H_;
#pragma unroll 2
        for (int kc = 0; kc < H_; kc += 64) {
            bf16x8 bi0[3], bi1[3];
#pragma unroll
            for (int ct = 0; ct < 3; ++ct) {
                const int ctg = cset * 3 + ct;
                const ushort* wr = Wihb +
                    (size_t)((ctg >> 1) * H_ + jb + (ctg & 1) * 16 + l15) * H_ + kc + quad * 8;
                bi0[ct] = *(const bf16x8*)wr;
                bi1[ct] = *(const bf16x8*)(wr + 32);
            }
            float cf[16];
            *(float4*)&cf[0]  = *(const float4*)(crow + kc + quad * 8);
            *(float4*)&cf[4]  = *(const float4*)(crow + kc + quad * 8 + 4);
            *(float4*)&cf[8]  = *(const float4*)(crow + kc + 32 + quad * 8);
            *(float4*)&cf[12] = *(const float4*)(crow + kc + 32 + quad * 8 + 4);
            __align__(16) ushort cb[16];
#pragma unroll
            for (int u = 0; u < 16; ++u) cb[u] = f2bf(cf[u]);
            const bf16x8 ac0 = *(const bf16x8*)&cb[0];
            const bf16x8 ac1 = *(const bf16x8*)&cb[8];
#pragma unroll
            for (int ct = 0; ct < 3; ++ct)
                accA[ct] = __builtin_amdgcn_mfma_f32_16x16x32_bf16(ac0, bi0[ct], accA[ct], 0, 0, 0);
#pragma unroll
            for (int ct = 0; ct < 3; ++ct)
                accA[ct] = __builtin_amdgcn_mfma_f32_16x16x32_bf16(ac1, bi1[ct], accA[ct], 0, 0, 0);
        }
    };

    // --- prologue: t=0. h0 ready (stream-ordered memset). C/G ready. ---
    zero_acc();
    phaseB(0);
    load_h(0);
    write_As(0);
    __syncthreads();

#pragma unroll 1
    for (int tstep = 0; tstep < S_; ++tstep) {
        float g_[2];
#pragma unroll
        for (int r2 = 0; r2 < 2; ++r2)
            g_[r2] = G[(size_t)(bb + wv * 8 + quad * 2 + r2) * S_ + tstep];

        float hold_[2][2];

        // ---------------- PhaseA: h(t-1) @ Whh over kc (LDS dbuf) -----------
        for (int kc = 0; kc < H_; kc += 64) {
            const int cur = (kc >> 6) & 1;
            const int kn  = kc + 64;
            if (kn < H_) load_h(kn);                 // prefetch next chunk
            const ushort* Ah = AsU + (cur * 2 + 0) * 4608;
            const ushort* Al = AsU + (cur * 2 + 1) * 4608;
#pragma unroll
            for (int ks2 = 0; ks2 < 2; ++ks2) {
                const int ao = ks2 * 32 + quad * 8;
                const int ai = (mh * 16 + l15) * 72 + ao;
                const bf16x8 a_hh = *(const bf16x8*)&Ah[ai];
                const bf16x8 a_hl = *(const bf16x8*)&Al[ai];
#pragma unroll
                for (int ct = 0; ct < 3; ++ct) {
                    const int ctg = cset * 3 + ct;
                    const bf16x8 bh = *(const bf16x8*)
                        &Whh_s[((ctg >> 1) * 32 + (ctg & 1) * 16 + l15) * 520 + kc + ao];
                    if (cset == 1 && ct >= 1) {      // n-gate: hn plane
                        accB[ct - 1] = __builtin_amdgcn_mfma_f32_16x16x32_bf16(a_hh, bh, accB[ct - 1], 0, 0, 0);
                        accB[ct - 1] = __builtin_amdgcn_mfma_f32_16x16x32_bf16(a_hl, bh, accB[ct - 1], 0, 0, 0);
                    } else {                         // r/z (and xn stays PhaseB-only)
                        accA[ct] = __builtin_amdgcn_mfma_f32_16x16x32_bf16(a_hh, bh, accA[ct], 0, 0, 0);
                        accA[ct] = __builtin_amdgcn_mfma_f32_16x16x32_bf16(a_hl, bh, accA[ct], 0, 0, 0);
                    }
                }
            }
            if (kc == hold_kc) {                     // h_old for own j-cols
#pragma unroll
                for (int nt = 0; nt < 2; ++nt)
#pragma unroll
                    for (int r2 = 0; r2 < 2; ++r2) {
                        const int ai = (wv * 8 + quad * 2 + r2) * 72 + hold_off + nt * 16 + l15;
                        hold_[nt][r2] = bf2f(Ah[ai]) + bf2f(Al[ai]);
                    }
            }
            if (kn < H_) write_As(cur ^ 1);          // stage next chunk (dbuf)
            __syncthreads();
        }

        // ---------------- epilogue: exchange gate partials via LDS ----------
#pragma unroll
        for (int ct = 0; ct < 3; ++ct) {
            const int ctg = cset * 3 + ct;
            const int go  = ctg >> 1;                // 0:r 1:z 2:xn
            const int col = (ctg & 1) * 16 + l15;
            const int rbase = mh * 16 + quad * 4;
#pragma unroll
            for (int r = 0; r < 4; ++r)
                gs[go * 2304 + (rbase + r) * 36 + col] = accA[ct][r];
            if (cset == 1 && ct >= 1) {              // hn plane
#pragma unroll
                for (int r = 0; r < 4; ++r)
                    gs[3 * 2304 + (rbase + r) * 36 + col] = accB[ct - 1][r];
            }
        }
        __syncthreads();

        const int last = (tstep == S_ - 1);
#pragma unroll
        for (int nt = 0; nt < 2; ++nt) {
            const int j = jb + nt * 16 + l15;
#pragma unroll
            for (int r2 = 0; r2 < 2; ++r2) {
                const int row = wv * 8 + quad * 2 + r2;
                const size_t idx = (size_t)(bb + row) * H_ + j;
                const int gidx = row * 36 + nt * 16 + l15;
                const float rrv = gs[0 * 2304 + gidx];
                const float zzv = gs[1 * 2304 + gidx];
                const float xnv = gs[2 * 2304 + gidx];
                const float hnv = gs[3 * 2304 + gidx];
                const float hold = hold_[nt][r2];
                const float g = g_[r2];
                const float rg = 1.f / (1.f + expf(-(rrv + br_[nt])));
                const float zg = 1.f / (1.f + expf(-(zzv + bz_[nt])));
                const float ng = tanhf(xnv + bxn_[nt] + rg * (hnv + bhn_[nt]));
                const float hgru = (1.f - zg) * ng + zg * hold;
                const float hnew = g * hgru + (1.f - g) * hold;
                const ushort hb = f2bf(hnew);
                const ushort hl = f2bf(hnew - bf2f(hb));
                __hip_atomic_store(&hw[idx], ((uint)hb << 16) | (uint)hl,
                                   __ATOMIC_RELAXED, __HIP_MEMORY_SCOPE_AGENT);
                if (last) out[idx] = hnew;
            }
        }
        if (last) break;

        // ---------------- flag -> PhaseB(t+1) -> poll -----------------------
        asm volatile("s_waitcnt vmcnt(0)" ::: "memory");   // h stores at coherence pt
        __syncthreads();                                   // all waves drained
        if (t == 0)
            __hip_atomic_store(&g_prog[(bt << 4) + jt], vbase + (unsigned)(tstep + 1),
                               __ATOMIC_RELAXED, __HIP_MEMORY_SCOPE_AGENT);
        { uint* tmp = hw; hw = (uint*)hr; hr = (const uint*)tmp; }

        zero_acc();
        phaseB(tstep + 1);          // h-independent work hides the barrier

        {   // per-wave poll: proceed as soon as all 16 members flagged
            const unsigned tgt = vbase + (unsigned)(tstep + 1);
            const int slot = (bt << 4) + (lane & 15);
            while (true) {
                const unsigned v = __hip_atomic_load(&g_prog[slot],
                                                     __ATOMIC_RELAXED, __HIP_MEMORY_SCOPE_AGENT);
                if (__all(v >= tgt)) break;
                __builtin_amdgcn_s_sleep(1);
            }
        }
        load_h(0);                  // h(t) readable now
        write_As(0);
        __syncthreads();
    }
}

extern "C" void kernel_launch(void* const* d_in, const int* in_sizes, int n_in,
                              void* d_out, int out_size, void* d_ws, size_t ws_size,
                              hipStream_t stream) {
    (void)in_sizes; (void)n_in; (void)out_size; (void)ws_size;
    const float* C    = (const float*)d_in[0];
    const float* Q    = (const float*)d_in[1];
    const float* M    = (const float*)d_in[2];
    const float* fc1w = (const float*)d_in[3];
    const float* fc1b = (const float*)d_in[4];
    const float* fc2w = (const float*)d_in[5];
    const float* fc2b = (const float*)d_in[6];
    const float* Wih  = (const float*)d_in[7];
    const float* Whh  = (const float*)d_in[8];
    const float* bih  = (const float*)d_in[9];
    const float* bhh  = (const float*)d_in[10];
    float* out = (float*)d_out;

    char* ws = (char*)d_ws;
    float* Gbuf  = (float*)ws;                           // 256 KB
    uint*  hp0   = (uint*)(ws + 262144);                 // 2 MB (packed h, buf 0)
    uint*  hp1   = (uint*)(ws + 262144 + 2097152);       // 2 MB (packed h, buf 1)
    ushort* fc1wb = (ushort*)(ws + 4456448);             // 480 KB
    ushort* Wihb  = (ushort*)(ws + 4947968);             // 1.5 MB
    ushort* Whhb  = (ushort*)(ws + 6520832);             // 1.5 MB (ends ~7.72 MB)

    // h0 = 0: zero packed buffer 0 (buffer 1 fully written at t=0)
    hipMemsetAsync(hp0, 0, 2097152, stream);

    prep_w<<<256, 256, 0, stream>>>(fc1w, fc1wb, Wih, Wihb, Whh, Whhb);
    g_kernel<<<B_, 256, 0, stream>>>(C, Q, M, fc1wb, fc1b, fc2w, fc2b, Gbuf);
    scan_all<<<256, 512, 0, stream>>>(C, Wihb, Whhb, bih, bhh, Gbuf,
                                      hp0, hp1, out);
}